// Round 2
// 269.552 us; speedup vs baseline: 1.0143x; 1.0143x over previous
//
#include <hip/hip_runtime.h>

#define DIM   1024
#define DST   16
#define NSEQ  8192
#define NB    4

#define MT    64      // rows (n) per tile
#define KC    128     // K-chunk staged per iteration
#define KCP   132     // padded LDS row stride (2-way bank aliasing max = free)
#define NTILE 128     // NSEQ / MT

// ---------------------------------------------------------------------------
// Kernel A: per 64-row tile, T = x_tile @ A (proven k1 loop), then intra-tile
// inclusive cumsum entirely in registers/LDS. Writes locally-scanned state
// Tloc[b][s][n] (2 MiB, L2/L3-resident) and per-tile totals TS[b][tile][s]
// (32 KB). Kernel boundary provides the device-wide sync + coherence.
// ---------------------------------------------------------------------------
__global__ __launch_bounds__(256) void kA_gemm_scan(
    const float* __restrict__ x, const float* __restrict__ A,
    float* __restrict__ Tloc, float* __restrict__ TS)
{
    __shared__ float xs[MT * KCP];        // 33,792 B
    __shared__ float at[DST * KCP];       //  8,448 B
    __shared__ float scanbuf[16 * DST];   //  1,024 B  [mg][s] row-group sums

    const int t    = threadIdx.x;
    const int b    = blockIdx.x >> 7;
    const int tile = blockIdx.x & 127;
    const int n0   = tile * MT;
    const int s    = t & 15;              // state index owned by this thread
    const int mg   = t >> 4;              // row-group 0..15 (4 rows each)

    const float* xrow = x + ((long)(b * NSEQ + n0)) * DIM;

    float acc0 = 0.f, acc1 = 0.f, acc2 = 0.f, acc3 = 0.f;

    for (int kc = 0; kc < DIM; kc += KC) {
        {   // stage x tile: 64 rows x 128 cols, coalesced float4
            const int q  = t & 31;
            const int r0 = t >> 5;
            #pragma unroll
            for (int it = 0; it < 8; ++it) {
                const int m = it * 8 + r0;
                const float4 v = *(const float4*)(xrow + (long)m * DIM + kc + 4 * q);
                *(float4*)&xs[m * KCP + 4 * q] = v;
            }
        }
        {   // stage A^T chunk: at[s][k] from A[k][s] (coalesced reads)
            #pragma unroll
            for (int it = 0; it < 8; ++it) {
                const int idx = it * 256 + t;
                const int kl  = idx >> 4;
                const int ss  = idx & 15;
                at[ss * KCP + kl] = A[(kc + kl) * DST + ss];
            }
        }
        __syncthreads();

        #pragma unroll 4
        for (int kq = 0; kq < KC / 4; ++kq) {
            const float4 a  = *(const float4*)&at[s * KCP + 4 * kq];
            const float4 x0 = *(const float4*)&xs[(mg * 4 + 0) * KCP + 4 * kq];
            const float4 x1 = *(const float4*)&xs[(mg * 4 + 1) * KCP + 4 * kq];
            const float4 x2 = *(const float4*)&xs[(mg * 4 + 2) * KCP + 4 * kq];
            const float4 x3 = *(const float4*)&xs[(mg * 4 + 3) * KCP + 4 * kq];
            acc0 += x0.x * a.x + x0.y * a.y + x0.z * a.z + x0.w * a.w;
            acc1 += x1.x * a.x + x1.y * a.y + x1.z * a.z + x1.w * a.w;
            acc2 += x2.x * a.x + x2.y * a.y + x2.z * a.z + x2.w * a.w;
            acc3 += x3.x * a.x + x3.y * a.y + x3.z * a.z + x3.w * a.w;
        }
        __syncthreads();
    }

    // ---- intra-tile inclusive scan over the 64 rows of this tile ----------
    const float rsum = acc0 + acc1 + acc2 + acc3;   // this thread's 4-row sum
    scanbuf[mg * DST + s] = rsum;
    __syncthreads();
    float excl = 0.f, total = 0.f;
    #pragma unroll
    for (int m = 0; m < 16; ++m) {
        const float v = scanbuf[m * DST + s];   // 16 banks + broadcast: conflict-free
        total += v;
        excl  += (m < mg) ? v : 0.f;
    }
    if (mg == 0) TS[((long)b * NTILE + tile) * DST + s] = total;

    const float c0 = excl + acc0;
    const float c1 = c0 + acc1;
    const float c2 = c1 + acc2;
    const float c3 = c2 + acc3;
    *(float4*)&Tloc[((long)(b * DST + s)) * NSEQ + n0 + mg * 4] =
        make_float4(c0, c1, c2, c3);
}

// ---------------------------------------------------------------------------
// Kernel B: per-tile prefix base = sum of preceding tile totals (TS is 8 KB
// per batch, L2-hot), then out = (Tloc + base) @ D with the proven k3 body.
// ---------------------------------------------------------------------------
__global__ __launch_bounds__(256) void kB_scan_out(
    const float* __restrict__ Tloc, const float* __restrict__ TS,
    const float* __restrict__ D, float* __restrict__ out)
{
    __shared__ float sp[MT * 20];         // [n][s] padded 16->20
    __shared__ float partial[16 * DST];   // [mg][s] partial prefix sums
    __shared__ float basebuf[DST];

    const int t    = threadIdx.x;
    const int b    = blockIdx.x >> 7;
    const int tile = blockIdx.x & 127;
    const int n0   = tile * MT;
    const int s    = t & 15;
    const int mg   = t >> 4;

    // D preload first so it overlaps the TS prefix loop
    float4 dreg[16];
    #pragma unroll
    for (int ss = 0; ss < 16; ++ss)
        dreg[ss] = *(const float4*)&D[ss * DIM + 4 * t];

    // distributed prefix: thread (s,mg) sums tiles j = mg, mg+16, ... < tile
    {
        const float* tsb = TS + (long)b * NTILE * DST;
        float p = 0.f;
        for (int j = mg; j < tile; j += 16) p += tsb[j * DST + s];
        partial[mg * DST + s] = p;
    }
    __syncthreads();
    {
        float bsum = 0.f;
        #pragma unroll
        for (int m = 0; m < 16; ++m) bsum += partial[m * DST + s];
        if (mg == 0) basebuf[s] = bsum;
    }
    __syncthreads();

    // stage state tile with base folded in: sp[nn][s] = Tloc[b][s][n0+nn]+base
    #pragma unroll
    for (int j = 0; j < 4; ++j) {
        const int idx = j * 256 + t;
        const int ss  = idx >> 6;     // wave-uniform -> basebuf broadcast
        const int nn  = idx & 63;
        sp[nn * 20 + ss] = Tloc[((long)(b * DST + ss)) * NSEQ + n0 + nn] + basebuf[ss];
    }
    __syncthreads();

    float* ob = out + ((long)(b * NSEQ + n0)) * DIM + 4 * t;
    for (int r = 0; r < MT; ++r) {
        const float4 s0 = *(const float4*)&sp[r * 20 + 0];
        const float4 s1 = *(const float4*)&sp[r * 20 + 4];
        const float4 s2 = *(const float4*)&sp[r * 20 + 8];
        const float4 s3 = *(const float4*)&sp[r * 20 + 12];
        const float sv[16] = {s0.x, s0.y, s0.z, s0.w, s1.x, s1.y, s1.z, s1.w,
                              s2.x, s2.y, s2.z, s2.w, s3.x, s3.y, s3.z, s3.w};
        float4 o = make_float4(0.f, 0.f, 0.f, 0.f);
        #pragma unroll
        for (int ss = 0; ss < 16; ++ss) {
            o.x += sv[ss] * dreg[ss].x;
            o.y += sv[ss] * dreg[ss].y;
            o.z += sv[ss] * dreg[ss].z;
            o.w += sv[ss] * dreg[ss].w;
        }
        *(float4*)(ob + (long)r * DIM) = o;
    }
}

// ---------------------------------------------------------------------------
extern "C" void kernel_launch(void* const* d_in, const int* in_sizes, int n_in,
                              void* d_out, int out_size, void* d_ws, size_t ws_size,
                              hipStream_t stream) {
    const float* x = (const float*)d_in[0];   // [4, 8192, 1024]
    const float* A = (const float*)d_in[1];   // [1024, 16]
    const float* D = (const float*)d_in[2];   // [16, 1024]
    float* out  = (float*)d_out;              // [4, 8192, 1024]
    float* Tloc = (float*)d_ws;               // [4, 16, 8192] = 2 MiB
    float* TS   = Tloc + (long)NB * DST * NSEQ;  // [4, 128, 16] = 32 KiB

    kA_gemm_scan<<<dim3(NB * NTILE), dim3(256), 0, stream>>>(x, A, Tloc, TS);
    kB_scan_out <<<dim3(NB * NTILE), dim3(256), 0, stream>>>(Tloc, TS, D, out);
}